// Round 12
// baseline (1082.170 us; speedup 1.0000x reference)
//
#include <hip/hip_runtime.h>

typedef unsigned short ushort_t;
typedef __bf16 bf16x8 __attribute__((ext_vector_type(8)));
typedef float f32x4 __attribute__((ext_vector_type(4)));
typedef unsigned short u16x8 __attribute__((ext_vector_type(8)));
typedef unsigned short u16x4 __attribute__((ext_vector_type(4)));

#define MFMA16(a, b, c) __builtin_amdgcn_mfma_f32_16x16x32_bf16(a, b, c, 0, 0, 0)

#define DIM 192
#define HEADS 6
#define GROUPS 8
#define CPG 24
#define HID 768
#define NWIN 4096
#define GN_N 1572864
#define SCALE 0.17677669529663687f

__device__ __forceinline__ ushort_t f2b(float f) {
  __bf16 h = (__bf16)f;
  return __builtin_bit_cast(unsigned short, h);
}
__device__ __forceinline__ float b2f(ushort_t u) {
  union { unsigned int u; float f; } v; v.u = ((unsigned int)u) << 16;
  return v.f;
}

// 8x8 transpose across lane-bits 3..5 vs register index (involution).
__device__ __forceinline__ void xpose8(ushort_t V[8], int C3) {
#pragma unroll
  for (int bb = 0; bb < 3; ++bb) {
    const int m = 1 << bb;
    int tt[8];
#pragma unroll
    for (int j = 0; j < 8; ++j) tt[j] = __shfl_xor((int)V[j], m << 3, 64);
#pragma unroll
    for (int j = 0; j < 8; ++j)
      if (((j >> bb) & 1) != ((C3 >> bb) & 1)) V[j] = (ushort_t)tt[j ^ m];
  }
}

// ---------------- weight transpose + bf16 convert: out[n][k] = in[k][n] ----
__global__ __launch_bounds__(256) void transpose_w(const float* __restrict__ in,
                                                   ushort_t* __restrict__ out,
                                                   int K, int N) {
  int id = blockIdx.x * 256 + threadIdx.x;
  if (id >= K * N) return;
  int n = id / K, k = id - n * K;
  out[id] = f2b(in[k * N + n]);
}

// ---------------- GroupNorm stats for x (fp32), stage 1 --------------------
__global__ __launch_bounds__(256) void gn_stats1_f32(const float* __restrict__ x,
                                                     float* __restrict__ partial) {
  int bid = blockIdx.x;           // 32 * 64
  int sg = bid >> 6, chunk = bid & 63;
  const float* p = x + (size_t)sg * GN_N + (size_t)chunk * 24576;
  int tid = threadIdx.x;
  float s = 0.f, s2 = 0.f;
#pragma unroll
  for (int i = 0; i < 24; ++i) {
    float4 v = *(const float4*)(p + (size_t)(i * 256 + tid) * 4);
    s += v.x + v.y + v.z + v.w;
    s2 += v.x * v.x + v.y * v.y + v.z * v.z + v.w * v.w;
  }
  for (int m = 1; m < 64; m <<= 1) { s += __shfl_xor(s, m); s2 += __shfl_xor(s2, m); }
  __shared__ float red[8];
  int wv = tid >> 6;
  if ((tid & 63) == 0) { red[wv * 2] = s; red[wv * 2 + 1] = s2; }
  __syncthreads();
  if (tid == 0) {
    float a = 0.f, b = 0.f;
    for (int i = 0; i < 4; ++i) { a += red[i * 2]; b += red[i * 2 + 1]; }
    partial[bid * 2] = a; partial[bid * 2 + 1] = b;
  }
}

__global__ __launch_bounds__(64) void gn_stats2(const float* __restrict__ partial,
                                                float* __restrict__ stats) {
  int sg = blockIdx.x;
  int lane = threadIdx.x;
  float s = partial[(sg * 64 + lane) * 2];
  float s2 = partial[(sg * 64 + lane) * 2 + 1];
  for (int m = 1; m < 64; m <<= 1) { s += __shfl_xor(s, m); s2 += __shfl_xor(s2, m); }
  if (lane == 0) {
    const float invN = 1.0f / (float)GN_N;
    float mean = s * invN;
    float var = s2 * invN - mean * mean;
    stats[sg * 2] = mean;
    stats[sg * 2 + 1] = rsqrtf(var + 1e-5f);
  }
}

// ---------------- GN2 reduce: per-window partials -> stats -----------------
__global__ __launch_bounds__(64) void gn2_reduce(const float2* __restrict__ gpart,
                                                 float* __restrict__ stats) {
  int bid = blockIdx.x;            // b*8 + g
  int b = bid >> 3, g = bid & 7;
  int lane = threadIdx.x;
  float s = 0.f, s2 = 0.f;
  for (int w = lane; w < 1024; w += 64) {
    float2 v = gpart[((size_t)b * 1024 + w) * 8 + g];
    s += v.x; s2 += v.y;
  }
  for (int m = 1; m < 64; m <<= 1) { s += __shfl_xor(s, m); s2 += __shfl_xor(s2, m); }
  if (lane == 0) {
    const float invN = 1.0f / (float)GN_N;
    float mean = s * invN;
    float var = s2 * invN - mean * mean;
    stats[bid * 2] = mean;
    stats[bid * 2 + 1] = rsqrtf(var + 1e-5f);
  }
}

// ---------------- norm1_win: GN1 + shift + windowize -> buf (bf16) ---------
__global__ __launch_bounds__(256) void norm1_win(
    const float* __restrict__ x, const float* __restrict__ stats1,
    const float* __restrict__ n1w, const float* __restrict__ n1b,
    ushort_t* __restrict__ buf) {
  int w = blockIdx.x;
  int b = w >> 10, wh = (w >> 5) & 31, ww = w & 31;
  int tid = threadIdx.x;
  int wave = tid >> 6, lane = tid & 63;
  int C3 = lane >> 3, I = lane & 7;

  __shared__ __align__(16) ushort_t tile[64][200];
  __shared__ float gwt[192], gbt[192];

  if (tid < 192) {
    int g = tid / 24;
    float mean = stats1[(b * 8 + g) * 2], rstd = stats1[(b * 8 + g) * 2 + 1];
    float w_ = n1w[tid] * rstd;
    gwt[tid] = w_;
    gbt[tid] = n1b[tid] - mean * w_;
  }
  __syncthreads();

  int px0 = (ww << 3) + 4;
  int px1 = (px0 + 4) & 255;

#pragma unroll
  for (int it = 0; it < 6; ++it) {
    int u = it * 256 + tid;
    int c = u >> 3, i = u & 7;
    int py = ((wh << 3) + i + 4) & 255;
    const float* src = x + (((size_t)(b * DIM + c)) << 16) + (py << 8);
    float4 ra = *(const float4*)(src + px0);
    float4 rb = *(const float4*)(src + px1);
    float gw = gwt[c], gb = gbt[c];
    ushort_t V[8];
    V[0] = f2b(fmaf(ra.x, gw, gb)); V[1] = f2b(fmaf(ra.y, gw, gb));
    V[2] = f2b(fmaf(ra.z, gw, gb)); V[3] = f2b(fmaf(ra.w, gw, gb));
    V[4] = f2b(fmaf(rb.x, gw, gb)); V[5] = f2b(fmaf(rb.y, gw, gb));
    V[6] = f2b(fmaf(rb.z, gw, gb)); V[7] = f2b(fmaf(rb.w, gw, gb));
    xpose8(V, C3);   // V[j] = xn(channel cbase+j, token I*8+C3)
    u16x8 wv;
#pragma unroll
    for (int j = 0; j < 8; ++j) wv[j] = V[j];
    int cbase = it * 32 + wave * 8;
    *(u16x8*)&tile[I * 8 + C3][cbase] = wv;
  }
  __syncthreads();

  ushort_t* bw = buf + (size_t)w * 12288;
#pragma unroll
  for (int it = 0; it < 6; ++it) {
    int u = it * 256 + tid;
    int token = u / 24, cv = u - token * 24;
    *(u16x8*)&bw[u * 8] = *(const u16x8*)&tile[token][cv * 8];
  }
}

// One qkv+attention pass for heads PH*2, PH*2+1.  PH literal (rule #20).
#define QKV_ATTN_PASS(PH)                                                      \
  {                                                                            \
    {                                                                          \
      int sec = wave >> 2;              /* 0=q 1=k 2=v */                      \
      int tloc = wave & 3;                                                     \
      int cols16 = sec * 192 + (PH) * 64 + tloc * 16;                          \
      int lh = tloc >> 1;                                                      \
      int d = ((tloc & 1) << 4) + p;                                           \
      f32x4 acc0 = zz, acc1 = zz, acc2 = zz, acc3 = zz;                        \
      _Pragma("unroll")                                                        \
      for (int ks = 0; ks < 6; ++ks) {                                         \
        int k0 = ks * 32 + q8 * 8;                                             \
        bf16x8 bfr = *(const bf16x8*)(qkvT + (size_t)(cols16 + p) * DIM + k0); \
        acc0 = MFMA16(*(const bf16x8*)&tile[0 * 16 + p][k0], bfr, acc0);       \
        acc1 = MFMA16(*(const bf16x8*)&tile[1 * 16 + p][k0], bfr, acc1);       \
        acc2 = MFMA16(*(const bf16x8*)&tile[2 * 16 + p][k0], bfr, acc2);       \
        acc3 = MFMA16(*(const bf16x8*)&tile[3 * 16 + p][k0], bfr, acc3);       \
      }                                                                        \
      float bias = qkv_b[cols16 + p];                                          \
      f32x4 a_[4] = {acc0, acc1, acc2, acc3};                                  \
      if (sec == 0) {                                                          \
        _Pragma("unroll")                                                      \
        for (int mt = 0; mt < 4; ++mt)                                         \
          _Pragma("unroll")                                                    \
          for (int r = 0; r < 4; ++r)                                          \
            qkP[lh][(mt * 16 + q8 * 4 + r) * 40 + d] =                         \
                f2b((a_[mt][r] + bias) * SCALE);                               \
      } else if (sec == 1) {                                                   \
        _Pragma("unroll")                                                      \
        for (int mt = 0; mt < 4; ++mt)                                         \
          _Pragma("unroll")                                                    \
          for (int r = 0; r < 4; ++r)                                          \
            qkP[lh][2560 + (mt * 16 + q8 * 4 + r) * 40 + d] =                  \
                f2b(a_[mt][r] + bias);                                         \
      } else {                                                                 \
        _Pragma("unroll")                                                      \
        for (int mt = 0; mt < 4; ++mt) {                                       \
          u16x4 vv;                                                            \
          _Pragma("unroll")                                                    \
          for (int r = 0; r < 4; ++r) vv[r] = f2b(a_[mt][r] + bias);           \
          *(u16x4*)&vT[lh][d * 72 + mt * 16 + q8 * 4] = vv;                    \
        }                                                                      \
      }                                                                        \
    }                                                                          \
    __syncthreads(); /* B2 */                                                  \
    {                                                                          \
      int lh = (wave >> 2) & 1, quad = wave & 3;                               \
      int rb_ = quad << 4;                                                     \
      int k0 = q8 * 8;                                                         \
      f32x4 s0 = zz, s1 = zz, s2 = zz, s3 = zz;                                \
      if (wave < 8) {                                                          \
        const ushort_t* qh = &qkP[lh][0];                                      \
        const ushort_t* kh = &qkP[lh][2560];                                   \
        bf16x8 aq = *(const bf16x8*)&qh[(rb_ + p) * 40 + k0];                  \
        bf16x8 bk0 = *(const bf16x8*)&kh[(0 + p) * 40 + k0];                   \
        bf16x8 bk1 = *(const bf16x8*)&kh[(16 + p) * 40 + k0];                  \
        bf16x8 bk2 = *(const bf16x8*)&kh[(32 + p) * 40 + k0];                  \
        bf16x8 bk3 = *(const bf16x8*)&kh[(48 + p) * 40 + k0];                  \
        s0 = MFMA16(aq, bk0, zz);                                              \
        s1 = MFMA16(aq, bk1, zz);                                              \
        s2 = MFMA16(aq, bk2, zz);                                              \
        s3 = MFMA16(aq, bk3, zz);                                              \
      }                                                                        \
      __syncthreads(); /* B3: q/k reads done before P overwrite */             \
      if (wave < 8) {                                                          \
        ushort_t* Ph = &qkP[lh][0];                                            \
        _Pragma("unroll")                                                      \
        for (int r = 0; r < 4; ++r) {                                          \
          float m = fmaxf(fmaxf(s0[r], s1[r]), fmaxf(s2[r], s3[r]));           \
          for (int msk = 1; msk < 16; msk <<= 1) m = fmaxf(m, __shfl_xor(m, msk)); \
          float e0 = __expf(s0[r] - m);                                        \
          float e1 = __expf(s1[r] - m);                                        \
          float e2 = __expf(s2[r] - m);                                        \
          float e3 = __expf(s3[r] - m);                                        \
          float sum = e0 + e1 + e2 + e3;                                       \
          for (int msk = 1; msk < 16; msk <<= 1) sum += __shfl_xor(sum, msk);  \
          float inv = 1.0f / sum;                                              \
          int row = rb_ + q8 * 4 + r;                                          \
          Ph[row * 72 + 0 + p]  = f2b(e0 * inv);                               \
          Ph[row * 72 + 16 + p] = f2b(e1 * inv);                               \
          Ph[row * 72 + 32 + p] = f2b(e2 * inv);                               \
          Ph[row * 72 + 48 + p] = f2b(e3 * inv);                               \
        }                                                                      \
        f32x4 o0 = zz, o1 = zz;                                                \
        _Pragma("unroll")                                                      \
        for (int ks = 0; ks < 2; ++ks) {                                       \
          int kk = ks * 32 + k0;                                               \
          bf16x8 bv0 = *(const bf16x8*)&vT[lh][(0 + p) * 72 + kk];             \
          bf16x8 bv1 = *(const bf16x8*)&vT[lh][(16 + p) * 72 + kk];            \
          bf16x8 ap = *(const bf16x8*)&Ph[(rb_ + p) * 72 + kk];                \
          o0 = MFMA16(ap, bv0, o0);                                            \
          o1 = MFMA16(ap, bv1, o1);                                            \
        }                                                                      \
        size_t ob = (size_t)w * 12288 + (size_t)(rb_ + q8 * 4) * 192 +         \
                    ((PH) * 2 + lh) * 32 + p;                                  \
        _Pragma("unroll")                                                      \
        for (int r = 0; r < 4; ++r) {                                          \
          obuf[ob + (size_t)r * 192]      = f2b(o0[r]);                        \
          obuf[ob + (size_t)r * 192 + 16] = f2b(o1[r]);                        \
        }                                                                      \
      }                                                                        \
    }                                                                          \
  }

// ---------------- K_a: qkv + attention (reads windowed xn; O in place) -----
__global__ __launch_bounds__(768, 3) void attn_kernel(
    const ushort_t* __restrict__ buf_xn,   // windowed xn (read), also O dest
    const ushort_t* __restrict__ qkvT, const float* __restrict__ qkv_b,
    ushort_t* __restrict__ obuf) {
  int w = blockIdx.x;
  int tid = threadIdx.x;
  int wave = tid >> 6, lane = tid & 63;
  int p = lane & 15, q8 = lane >> 4;

  __shared__ __align__(16) ushort_t tile[64][200];  // xn (token-major) 25600 B
  __shared__ __align__(16) ushort_t qkP[2][5120];   // q|k -> P, per head 10240 B
  __shared__ __align__(16) ushort_t vT[2][2304];    // v^T [32][72] 4608 B/head

  // ---- phase 0: coalesced copy buf -> tile ----
  const ushort_t* bw = buf_xn + (size_t)w * 12288;
#pragma unroll
  for (int it = 0; it < 2; ++it) {
    int u = it * 768 + tid;
    int token = u / 24, cv = u - token * 24;
    *(u16x8*)&tile[token][cv * 8] = *(const u16x8*)&bw[u * 8];
  }
  __syncthreads();   // B1

  const f32x4 zz = {0.f, 0.f, 0.f, 0.f};

  QKV_ATTN_PASS(0)
  __syncthreads();   // B4
  QKV_ATTN_PASS(1)
  __syncthreads();   // B4
  QKV_ATTN_PASS(2)
}

// ---------------- K_b: proj GEMM + residual-1 -> x_mid (in place) ----------
__global__ __launch_bounds__(256) void proj_kernel(
    ushort_t* __restrict__ buf,           // in: O, out: x_mid (windowed)
    const ushort_t* __restrict__ projT, const float* __restrict__ proj_b,
    const float* __restrict__ x, float2* __restrict__ gpart) {
  int w = blockIdx.x;
  int b = w >> 10, wh = (w >> 5) & 31, ww = w & 31;
  int tid = threadIdx.x;
  int wave = tid >> 6, lane = tid & 63;
  int p = lane & 15, q8 = lane >> 4;
  int C3 = lane >> 3, I = lane & 7;

  __shared__ __align__(16) ushort_t otile[64][200];  // O -> proj-out -> resid
  __shared__ __align__(16) float2 red[1536];

  ushort_t* bw = buf + (size_t)w * 12288;

  // ---- load O tile (coalesced) ----
#pragma unroll
  for (int it = 0; it < 6; ++it) {
    int idx = (it * 256 + tid) * 8;       // entry index, 8-aligned
    int t = idx / 192, c = idx - t * 192;
    *(u16x8*)&otile[t][c] = *(const u16x8*)&bw[idx];
  }
  __syncthreads();

  // ---- proj GEMM: 12 col-tiles over 4 waves (3 rounds, static acc) ----
  const f32x4 zz = {0.f, 0.f, 0.f, 0.f};
  f32x4 prr[3][4];
#pragma unroll
  for (int rd = 0; rd < 3; ++rd) {
    int col = rd * 64 + wave * 16 + p;
#pragma unroll
    for (int mt = 0; mt < 4; ++mt) prr[rd][mt] = zz;
#pragma unroll
    for (int ks = 0; ks < 6; ++ks) {
      int k0 = ks * 32 + q8 * 8;
      bf16x8 bfr = *(const bf16x8*)(projT + (size_t)col * DIM + k0);
      prr[rd][0] = MFMA16(*(const bf16x8*)&otile[0 * 16 + p][k0], bfr, prr[rd][0]);
      prr[rd][1] = MFMA16(*(const bf16x8*)&otile[1 * 16 + p][k0], bfr, prr[rd][1]);
      prr[rd][2] = MFMA16(*(const bf16x8*)&otile[2 * 16 + p][k0], bfr, prr[rd][2]);
      prr[rd][3] = MFMA16(*(const bf16x8*)&otile[3 * 16 + p][k0], bfr, prr[rd][3]);
    }
  }
  __syncthreads();   // all otile reads done

  // ---- write proj-out (+bias) back into otile ----
#pragma unroll
  for (int rd = 0; rd < 3; ++rd) {
    int col = rd * 64 + wave * 16 + p;
    float bias = proj_b[col];
#pragma unroll
    for (int mt = 0; mt < 4; ++mt)
#pragma unroll
      for (int r = 0; r < 4; ++r)
        otile[mt * 16 + q8 * 4 + r][col] = f2b(prr[rd][mt][r] + bias);
  }
  __syncthreads();

  int px0 = (ww << 3) + 4;
  int px1 = (px0 + 4) & 255;

  // ---- in-place residual (token-major via xpose8) ----
#pragma unroll
  for (int it = 0; it < 6; ++it) {
    int u = it * 256 + tid;
    int c = u >> 3, i = u & 7;
    int cbase = it * 32 + wave * 8;
    u16x8 rr = *(const u16x8*)&otile[I * 8 + C3][cbase];
    ushort_t V[8];
#pragma unroll
    for (int j = 0; j < 8; ++j) V[j] = rr[j];
    xpose8(V, C3);   // V[j] = proj-out(channel c, token i*8+j)
    int py = ((wh << 3) + i + 4) & 255;
    const float* src = x + (((size_t)(b * DIM + c)) << 16) + (py << 8);
    float4 ra = *(const float4*)(src + px0);
    V[0] = f2b(ra.x + b2f(V[0]));
    V[1] = f2b(ra.y + b2f(V[1]));
    V[2] = f2b(ra.z + b2f(V[2]));
    V[3] = f2b(ra.w + b2f(V[3]));
    float4 rb2 = *(const float4*)(src + px1);
    V[4] = f2b(rb2.x + b2f(V[4]));
    V[5] = f2b(rb2.y + b2f(V[5]));
    V[6] = f2b(rb2.z + b2f(V[6]));
    V[7] = f2b(rb2.w + b2f(V[7]));
    xpose8(V, C3);   // back to (channel cbase+j, token I*8+C3)
    u16x8 wv;
#pragma unroll
    for (int j = 0; j < 8; ++j) wv[j] = V[j];
    *(u16x8*)&otile[I * 8 + C3][cbase] = wv;   // same addr as read: wave-local RMW
  }
  __syncthreads();

  // ---- coalesced write back to buf (now x_mid) + GN2 partials ----
#pragma unroll
  for (int it = 0; it < 6; ++it) {
    int u = it * 256 + tid;
    int token = u / 24, cv = u - token * 24;
    u16x8 v = *(const u16x8*)&otile[token][cv * 8];
    *(u16x8*)&bw[u * 8] = v;
    float s_ = 0.f, s2_ = 0.f;
#pragma unroll
    for (int t = 0; t < 8; ++t) { float f = b2f(v[t]); s_ += f; s2_ += f * f; }
    red[u] = make_float2(s_, s2_);
  }
  __syncthreads();

  for (int g = wave; g < 8; g += 4) {
    float s_ = 0.f, s2_ = 0.f;
#pragma unroll
    for (int j = 0; j < 3; ++j) {
      float2 t_ = red[lane * 24 + g * 3 + j];
      s_ += t_.x; s2_ += t_.y;
    }
    for (int m = 1; m < 64; m <<= 1) { s_ += __shfl_xor(s_, m); s2_ += __shfl_xor(s2_, m); }
    if (lane == 0) gpart[(size_t)w * 8 + g] = make_float2(s_, s2_);
  }
}

// ---------------- fused GN2 + MLP + residual2 ------------------------------
// 6 waves (384 thr), chunk=96: GEMM1 1 tile/wave, GEMM2 2 tiles/wave, balanced.
// LDS 40448 B -> 4 blocks/CU = 24 waves (75% ceiling). Latency-bound -> TLP.
__global__ __launch_bounds__(384, 4) void mlp_kernel(
    const ushort_t* __restrict__ x_mid,
    const ushort_t* __restrict__ w1T, const float* __restrict__ b1,
    const ushort_t* __restrict__ w2T, const float* __restrict__ b2,
    const float* __restrict__ stats2,
    const float* __restrict__ n2w, const float* __restrict__ n2b,
    float* __restrict__ out) {
  int bid = blockIdx.x;
  int b = bid >> 10, y = (bid >> 2) & 255, xq = bid & 3;
  int x0 = xq * 64;
  int tid = threadIdx.x;
  int wave = tid >> 6, lane = tid & 63;
  int p = lane & 15, q = lane >> 4;

  __shared__ ushort_t xn[64][200];   // xn tile (token-major), later mlp-out staging
  __shared__ ushort_t hb[64][104];   // hidden chunk [token][0..95], 16B-aligned rows
  __shared__ float gw2[192], gb2[192];

  int yp = (y + 252) & 255;          // (y - 4) mod 256
  int whp = yp >> 3, ip = yp & 7;
  size_t winrow = ((size_t)b * 1024 + (size_t)whp * 32) * 12288;

  if (tid < 192) {
    int g = tid / 24;
    float mean = stats2[(b * 8 + g) * 2], rstd = stats2[(b * 8 + g) * 2 + 1];
    float w_ = n2w[tid] * rstd;
    gw2[tid] = w_;
    gb2[tid] = n2b[tid] - mean * w_;
  }
  __syncthreads();

  for (int u = tid; u < 1536; u += 384) {
    int tx = u / 24, ch = u - tx * 24;
    int c8 = ch * 8;
    int xp = (x0 + tx + 252) & 255;  // (x - 4) mod 256
    u16x8 v = *(const u16x8*)(x_mid + winrow + (size_t)(xp >> 3) * 12288 +
                              (size_t)(ip * 8 + (xp & 7)) * 192 + c8);
    u16x8 o;
#pragma unroll
    for (int t = 0; t < 8; ++t) {
      int c = c8 + t;
      o[t] = f2b(fmaf(b2f(v[t]), gw2[c], gb2[c]));
    }
    *(u16x8*)&xn[tx][c8] = o;
  }
  __syncthreads();

  const f32x4 zz = {0.f, 0.f, 0.f, 0.f};
  f32x4 accO[4][2];
#pragma unroll
  for (int mt = 0; mt < 4; ++mt)
#pragma unroll
    for (int nt = 0; nt < 2; ++nt) accO[mt][nt] = zz;

#pragma unroll 1
  for (int ch = 0; ch < 8; ++ch) {
    // GEMM1 (swapped): wave's 16 hidden cols; a1[mt] = D[hid][token]
    int hbase = ch * 96 + wave * 16;
    f32x4 a1[4];
#pragma unroll
    for (int mt = 0; mt < 4; ++mt) a1[mt] = zz;
#pragma unroll
    for (int ks = 0; ks < 6; ++ks) {
      int k0 = ks * 32 + q * 8;
      bf16x8 wf = *(const bf16x8*)(w1T + (size_t)(hbase + p) * DIM + k0);
#pragma unroll
      for (int mt = 0; mt < 4; ++mt) {
        bf16x8 xf = *(const bf16x8*)&xn[mt * 16 + p][k0];
        a1[mt] = MFMA16(wf, xf, a1[mt]);
      }
    }
    float4 bb = *(const float4*)&b1[hbase + q * 4];
    if (ch) __syncthreads();     // previous chunk's GEMM2 hb readers done
#pragma unroll
    for (int mt = 0; mt < 4; ++mt) {
      u16x4 hv;
#pragma unroll
      for (int r = 0; r < 4; ++r) {
        float vv = a1[mt][r] + ((const float*)&bb)[r];
        float g = vv / (1.0f + __expf(-1.702f * vv));   // sigmoid-GELU
        hv[r] = f2b(g);
      }
      *(u16x4*)&hb[mt * 16 + p][wave * 16 + q * 4] = hv;
    }
    __syncthreads();
    // GEMM2 (swapped): wave's 32 out cols; accO[mt][nt] = D[outcol][token]
#pragma unroll
    for (int ks = 0; ks < 3; ++ks) {
      int k0 = ks * 32 + q * 8;
      bf16x8 w20 = *(const bf16x8*)(w2T + (size_t)(wave * 32 + 0  + p) * HID + ch * 96 + k0);
      bf16x8 w21 = *(const bf16x8*)(w2T + (size_t)(wave * 32 + 16 + p) * HID + ch * 96 + k0);
#pragma unroll
      for (int mt = 0; mt < 4; ++mt) {
        bf16x8 hf = *(const bf16x8*)&hb[mt * 16 + p][k0];
        accO[mt][0] = MFMA16(w20, hf, accO[mt][0]);
        accO[mt][1] = MFMA16(w21, hf, accO[mt][1]);
      }
    }
  }
  __syncthreads();

  // stage mlp-out (+b2) into xn via row-major u16x4 stores
#pragma unroll
  for (int nt = 0; nt < 2; ++nt) {
    float4 bb = *(const float4*)&b2[wave * 32 + nt * 16 + q * 4];
#pragma unroll
    for (int mt = 0; mt < 4; ++mt) {
      u16x4 ov;
#pragma unroll
      for (int r = 0; r < 4; ++r)
        ov[r] = f2b(accO[mt][nt][r] + ((const float*)&bb)[r]);
      *(u16x4*)&xn[mt * 16 + p][wave * 32 + nt * 16 + q * 4] = ov;
    }
  }
  __syncthreads();

  // coalesced fp32 out stores: wave = 64 consecutive x for one 8-ch chunk
#pragma unroll
  for (int cg = 0; cg < 4; ++cg) {
    int chunk = wave + cg * 6;                // 0..23
    int txx = lane;
    int c8 = chunk * 8;
    int xp = (x0 + txx + 252) & 255;
    u16x8 raw = *(const u16x8*)(x_mid + winrow + (size_t)(xp >> 3) * 12288 +
                                (size_t)(ip * 8 + (xp & 7)) * 192 + c8);
    u16x8 mo = *(const u16x8*)&xn[txx][c8];
#pragma unroll
    for (int t = 0; t < 8; ++t) {
      out[(((size_t)(b * DIM + c8 + t)) << 16) + (y << 8) + x0 + txx] =
          b2f(raw[t]) + b2f(mo[t]);
    }
  }
}

// ---------------- host launcher --------------------------------------------
extern "C" void kernel_launch(void* const* d_in, const int* in_sizes, int n_in,
                              void* d_out, int out_size, void* d_ws, size_t ws_size,
                              hipStream_t stream) {
  const float* x      = (const float*)d_in[0];
  const float* qkv_w  = (const float*)d_in[1];
  const float* qkv_b  = (const float*)d_in[2];
  const float* proj_w = (const float*)d_in[3];
  const float* proj_b = (const float*)d_in[4];
  const float* n1w    = (const float*)d_in[5];
  const float* n1b    = (const float*)d_in[6];
  const float* n2w    = (const float*)d_in[7];
  const float* n2b    = (const float*)d_in[8];
  const float* mlp_w1 = (const float*)d_in[9];
  const float* mlp_b1 = (const float*)d_in[10];
  const float* mlp_w2 = (const float*)d_in[11];
  const float* mlp_b2 = (const float*)d_in[12];
  float* out = (float*)d_out;

  char* ws = (char*)d_ws;
  const size_t XMID_B = (size_t)NWIN * 64 * DIM * 2;          // 100663296
  ushort_t* buf   = (ushort_t*)ws;     // xn_win -> O -> x_mid (same region)
  ushort_t* qkvT  = (ushort_t*)(ws + XMID_B);
  ushort_t* projT = (ushort_t*)(ws + XMID_B + 221184);
  ushort_t* w1T   = (ushort_t*)(ws + XMID_B + 221184 + 73728);
  ushort_t* w2T   = (ushort_t*)(ws + XMID_B + 221184 + 73728 + 294912);
  float* partial  = (float*)(ws + XMID_B + 884736);
  float* stats1   = (float*)(ws + XMID_B + 884736 + 16384);
  float* stats2   = (float*)(ws + XMID_B + 884736 + 16384 + 256);
  float2* gpart   = (float2*)(ws + XMID_B + 884736 + 16384 + 512);

  transpose_w<<<(576 * 192 + 255) / 256, 256, 0, stream>>>(qkv_w, qkvT, 192, 576);
  transpose_w<<<(192 * 192 + 255) / 256, 256, 0, stream>>>(proj_w, projT, 192, 192);
  transpose_w<<<(768 * 192 + 255) / 256, 256, 0, stream>>>(mlp_w1, w1T, 192, 768);
  transpose_w<<<(192 * 768 + 255) / 256, 256, 0, stream>>>(mlp_w2, w2T, 768, 192);

  gn_stats1_f32<<<32 * 64, 256, 0, stream>>>(x, partial);
  gn_stats2<<<32, 64, 0, stream>>>(partial, stats1);

  norm1_win<<<NWIN, 256, 0, stream>>>(x, stats1, n1w, n1b, buf);

  attn_kernel<<<NWIN, 768, 0, stream>>>(buf, qkvT, qkv_b, buf);

  proj_kernel<<<NWIN, 256, 0, stream>>>(buf, projT, proj_b, x, gpart);

  gn2_reduce<<<32, 64, 0, stream>>>(gpart, stats2);

  mlp_kernel<<<NWIN, 384, 0, stream>>>(buf, w1T, mlp_b1, w2T, mlp_b2,
                                       stats2, n2w, n2b, out);
}

// Round 13
// 1021.019 us; speedup vs baseline: 1.0599x; 1.0599x over previous
//
#include <hip/hip_runtime.h>

typedef unsigned short ushort_t;
typedef __bf16 bf16x8 __attribute__((ext_vector_type(8)));
typedef float f32x4 __attribute__((ext_vector_type(4)));
typedef unsigned short u16x8 __attribute__((ext_vector_type(8)));
typedef unsigned short u16x4 __attribute__((ext_vector_type(4)));

#define MFMA16(a, b, c) __builtin_amdgcn_mfma_f32_16x16x32_bf16(a, b, c, 0, 0, 0)

#define DIM 192
#define HEADS 6
#define GROUPS 8
#define CPG 24
#define HID 768
#define NWIN 4096
#define GN_N 1572864
#define SCALE 0.17677669529663687f

__device__ __forceinline__ ushort_t f2b(float f) {
  __bf16 h = (__bf16)f;
  return __builtin_bit_cast(unsigned short, h);
}
__device__ __forceinline__ float b2f(ushort_t u) {
  union { unsigned int u; float f; } v; v.u = ((unsigned int)u) << 16;
  return v.f;
}

// 8x8 transpose across lane-bits 3..5 vs register index (involution).
__device__ __forceinline__ void xpose8(ushort_t V[8], int C3) {
#pragma unroll
  for (int bb = 0; bb < 3; ++bb) {
    const int m = 1 << bb;
    int tt[8];
#pragma unroll
    for (int j = 0; j < 8; ++j) tt[j] = __shfl_xor((int)V[j], m << 3, 64);
#pragma unroll
    for (int j = 0; j < 8; ++j)
      if (((j >> bb) & 1) != ((C3 >> bb) & 1)) V[j] = (ushort_t)tt[j ^ m];
  }
}

// ---------------- weight transpose + bf16 convert: out[n][k] = in[k][n] ----
__global__ __launch_bounds__(256) void transpose_w(const float* __restrict__ in,
                                                   ushort_t* __restrict__ out,
                                                   int K, int N) {
  int id = blockIdx.x * 256 + threadIdx.x;
  if (id >= K * N) return;
  int n = id / K, k = id - n * K;
  out[id] = f2b(in[k * N + n]);
}

// ---------------- GroupNorm stats for x (fp32), stage 1 --------------------
__global__ __launch_bounds__(256) void gn_stats1_f32(const float* __restrict__ x,
                                                     float* __restrict__ partial) {
  int bid = blockIdx.x;           // 32 * 64
  int sg = bid >> 6, chunk = bid & 63;
  const float* p = x + (size_t)sg * GN_N + (size_t)chunk * 24576;
  int tid = threadIdx.x;
  float s = 0.f, s2 = 0.f;
#pragma unroll
  for (int i = 0; i < 24; ++i) {
    float4 v = *(const float4*)(p + (size_t)(i * 256 + tid) * 4);
    s += v.x + v.y + v.z + v.w;
    s2 += v.x * v.x + v.y * v.y + v.z * v.z + v.w * v.w;
  }
  for (int m = 1; m < 64; m <<= 1) { s += __shfl_xor(s, m); s2 += __shfl_xor(s2, m); }
  __shared__ float red[8];
  int wv = tid >> 6;
  if ((tid & 63) == 0) { red[wv * 2] = s; red[wv * 2 + 1] = s2; }
  __syncthreads();
  if (tid == 0) {
    float a = 0.f, b = 0.f;
    for (int i = 0; i < 4; ++i) { a += red[i * 2]; b += red[i * 2 + 1]; }
    partial[bid * 2] = a; partial[bid * 2 + 1] = b;
  }
}

__global__ __launch_bounds__(64) void gn_stats2(const float* __restrict__ partial,
                                                float* __restrict__ stats) {
  int sg = blockIdx.x;
  int lane = threadIdx.x;
  float s = partial[(sg * 64 + lane) * 2];
  float s2 = partial[(sg * 64 + lane) * 2 + 1];
  for (int m = 1; m < 64; m <<= 1) { s += __shfl_xor(s, m); s2 += __shfl_xor(s2, m); }
  if (lane == 0) {
    const float invN = 1.0f / (float)GN_N;
    float mean = s * invN;
    float var = s2 * invN - mean * mean;
    stats[sg * 2] = mean;
    stats[sg * 2 + 1] = rsqrtf(var + 1e-5f);
  }
}

// ---------------- GN2 reduce: per-window partials -> stats -----------------
__global__ __launch_bounds__(64) void gn2_reduce(const float2* __restrict__ gpart,
                                                 float* __restrict__ stats) {
  int bid = blockIdx.x;            // b*8 + g
  int b = bid >> 3, g = bid & 7;
  int lane = threadIdx.x;
  float s = 0.f, s2 = 0.f;
  for (int w = lane; w < 1024; w += 64) {
    float2 v = gpart[((size_t)b * 1024 + w) * 8 + g];
    s += v.x; s2 += v.y;
  }
  for (int m = 1; m < 64; m <<= 1) { s += __shfl_xor(s, m); s2 += __shfl_xor(s2, m); }
  if (lane == 0) {
    const float invN = 1.0f / (float)GN_N;
    float mean = s * invN;
    float var = s2 * invN - mean * mean;
    stats[bid * 2] = mean;
    stats[bid * 2 + 1] = rsqrtf(var + 1e-5f);
  }
}

// ---------------- norm1_win: GN1 + shift + windowize -> buf (bf16) ---------
__global__ __launch_bounds__(256) void norm1_win(
    const float* __restrict__ x, const float* __restrict__ stats1,
    const float* __restrict__ n1w, const float* __restrict__ n1b,
    ushort_t* __restrict__ buf) {
  int w = blockIdx.x;
  int b = w >> 10, wh = (w >> 5) & 31, ww = w & 31;
  int tid = threadIdx.x;
  int wave = tid >> 6, lane = tid & 63;
  int C3 = lane >> 3, I = lane & 7;

  __shared__ __align__(16) ushort_t tile[64][200];
  __shared__ float gwt[192], gbt[192];

  if (tid < 192) {
    int g = tid / 24;
    float mean = stats1[(b * 8 + g) * 2], rstd = stats1[(b * 8 + g) * 2 + 1];
    float w_ = n1w[tid] * rstd;
    gwt[tid] = w_;
    gbt[tid] = n1b[tid] - mean * w_;
  }
  __syncthreads();

  int px0 = (ww << 3) + 4;
  int px1 = (px0 + 4) & 255;

#pragma unroll
  for (int it = 0; it < 6; ++it) {
    int u = it * 256 + tid;
    int c = u >> 3, i = u & 7;
    int py = ((wh << 3) + i + 4) & 255;
    const float* src = x + (((size_t)(b * DIM + c)) << 16) + (py << 8);
    float4 ra = *(const float4*)(src + px0);
    float4 rb = *(const float4*)(src + px1);
    float gw = gwt[c], gb = gbt[c];
    ushort_t V[8];
    V[0] = f2b(fmaf(ra.x, gw, gb)); V[1] = f2b(fmaf(ra.y, gw, gb));
    V[2] = f2b(fmaf(ra.z, gw, gb)); V[3] = f2b(fmaf(ra.w, gw, gb));
    V[4] = f2b(fmaf(rb.x, gw, gb)); V[5] = f2b(fmaf(rb.y, gw, gb));
    V[6] = f2b(fmaf(rb.z, gw, gb)); V[7] = f2b(fmaf(rb.w, gw, gb));
    xpose8(V, C3);   // V[j] = xn(channel cbase+j, token I*8+C3)
    u16x8 wv;
#pragma unroll
    for (int j = 0; j < 8; ++j) wv[j] = V[j];
    int cbase = it * 32 + wave * 8;
    *(u16x8*)&tile[I * 8 + C3][cbase] = wv;
  }
  __syncthreads();

  ushort_t* bw = buf + (size_t)w * 12288;
#pragma unroll
  for (int it = 0; it < 6; ++it) {
    int u = it * 256 + tid;
    int token = u / 24, cv = u - token * 24;
    *(u16x8*)&bw[u * 8] = *(const u16x8*)&tile[token][cv * 8];
  }
}

// One qkv+attention pass for heads PH*2, PH*2+1.  PH literal (rule #20).
// Stores go DIRECTLY from named acc0..acc3 (no f32x4 a_[4] copy -> VGPR <= 64
// so two 12-wave blocks co-reside; VGPR 65-128 costs half the wave slots).
#define QKV_ATTN_PASS(PH)                                                      \
  {                                                                            \
    {                                                                          \
      int sec = wave >> 2;              /* 0=q 1=k 2=v */                      \
      int tloc = wave & 3;                                                     \
      int cols16 = sec * 192 + (PH) * 64 + tloc * 16;                          \
      int lh = tloc >> 1;                                                      \
      int d = ((tloc & 1) << 4) + p;                                           \
      f32x4 acc0 = zz, acc1 = zz, acc2 = zz, acc3 = zz;                        \
      _Pragma("unroll")                                                        \
      for (int ks = 0; ks < 6; ++ks) {                                         \
        int k0 = ks * 32 + q8 * 8;                                             \
        bf16x8 bfr = *(const bf16x8*)(qkvT + (size_t)(cols16 + p) * DIM + k0); \
        acc0 = MFMA16(*(const bf16x8*)&tile[0 * 16 + p][k0], bfr, acc0);       \
        acc1 = MFMA16(*(const bf16x8*)&tile[1 * 16 + p][k0], bfr, acc1);       \
        acc2 = MFMA16(*(const bf16x8*)&tile[2 * 16 + p][k0], bfr, acc2);       \
        acc3 = MFMA16(*(const bf16x8*)&tile[3 * 16 + p][k0], bfr, acc3);       \
      }                                                                        \
      float bias = qkv_b[cols16 + p];                                          \
      if (sec == 0) {                                                          \
        int base = q8 * 4;                                                     \
        _Pragma("unroll")                                                      \
        for (int r = 0; r < 4; ++r) {                                          \
          qkP[lh][(0 * 16 + base + r) * 40 + d] = f2b((acc0[r] + bias) * SCALE); \
          qkP[lh][(1 * 16 + base + r) * 40 + d] = f2b((acc1[r] + bias) * SCALE); \
          qkP[lh][(2 * 16 + base + r) * 40 + d] = f2b((acc2[r] + bias) * SCALE); \
          qkP[lh][(3 * 16 + base + r) * 40 + d] = f2b((acc3[r] + bias) * SCALE); \
        }                                                                      \
      } else if (sec == 1) {                                                   \
        int base = q8 * 4;                                                     \
        _Pragma("unroll")                                                      \
        for (int r = 0; r < 4; ++r) {                                          \
          qkP[lh][2560 + (0 * 16 + base + r) * 40 + d] = f2b(acc0[r] + bias);  \
          qkP[lh][2560 + (1 * 16 + base + r) * 40 + d] = f2b(acc1[r] + bias);  \
          qkP[lh][2560 + (2 * 16 + base + r) * 40 + d] = f2b(acc2[r] + bias);  \
          qkP[lh][2560 + (3 * 16 + base + r) * 40 + d] = f2b(acc3[r] + bias);  \
        }                                                                      \
      } else {                                                                 \
        u16x4 v0, v1, v2, v3;                                                  \
        _Pragma("unroll")                                                      \
        for (int r = 0; r < 4; ++r) {                                          \
          v0[r] = f2b(acc0[r] + bias);                                         \
          v1[r] = f2b(acc1[r] + bias);                                         \
          v2[r] = f2b(acc2[r] + bias);                                         \
          v3[r] = f2b(acc3[r] + bias);                                         \
        }                                                                      \
        int base = d * 72 + q8 * 4;                                            \
        *(u16x4*)&vT[lh][base + 0]  = v0;                                      \
        *(u16x4*)&vT[lh][base + 16] = v1;                                      \
        *(u16x4*)&vT[lh][base + 32] = v2;                                      \
        *(u16x4*)&vT[lh][base + 48] = v3;                                      \
      }                                                                        \
    }                                                                          \
    __syncthreads(); /* B2 */                                                  \
    {                                                                          \
      int lh = (wave >> 2) & 1, quad = wave & 3;                               \
      int rb_ = quad << 4;                                                     \
      int k0 = q8 * 8;                                                         \
      f32x4 s0 = zz, s1 = zz, s2 = zz, s3 = zz;                                \
      if (wave < 8) {                                                          \
        const ushort_t* qh = &qkP[lh][0];                                      \
        const ushort_t* kh = &qkP[lh][2560];                                   \
        bf16x8 aq = *(const bf16x8*)&qh[(rb_ + p) * 40 + k0];                  \
        bf16x8 bk0 = *(const bf16x8*)&kh[(0 + p) * 40 + k0];                   \
        bf16x8 bk1 = *(const bf16x8*)&kh[(16 + p) * 40 + k0];                  \
        bf16x8 bk2 = *(const bf16x8*)&kh[(32 + p) * 40 + k0];                  \
        bf16x8 bk3 = *(const bf16x8*)&kh[(48 + p) * 40 + k0];                  \
        s0 = MFMA16(aq, bk0, zz);                                              \
        s1 = MFMA16(aq, bk1, zz);                                              \
        s2 = MFMA16(aq, bk2, zz);                                              \
        s3 = MFMA16(aq, bk3, zz);                                              \
      }                                                                        \
      __syncthreads(); /* B3: q/k reads done before P overwrite */             \
      if (wave < 8) {                                                          \
        ushort_t* Ph = &qkP[lh][0];                                            \
        _Pragma("unroll")                                                      \
        for (int r = 0; r < 4; ++r) {                                          \
          float m = fmaxf(fmaxf(s0[r], s1[r]), fmaxf(s2[r], s3[r]));           \
          for (int msk = 1; msk < 16; msk <<= 1) m = fmaxf(m, __shfl_xor(m, msk)); \
          float e0 = __expf(s0[r] - m);                                        \
          float e1 = __expf(s1[r] - m);                                        \
          float e2 = __expf(s2[r] - m);                                        \
          float e3 = __expf(s3[r] - m);                                        \
          float sum = e0 + e1 + e2 + e3;                                       \
          for (int msk = 1; msk < 16; msk <<= 1) sum += __shfl_xor(sum, msk);  \
          float inv = 1.0f / sum;                                              \
          int row = rb_ + q8 * 4 + r;                                          \
          Ph[row * 72 + 0 + p]  = f2b(e0 * inv);                               \
          Ph[row * 72 + 16 + p] = f2b(e1 * inv);                               \
          Ph[row * 72 + 32 + p] = f2b(e2 * inv);                               \
          Ph[row * 72 + 48 + p] = f2b(e3 * inv);                               \
        }                                                                      \
        f32x4 o0 = zz, o1 = zz;                                                \
        _Pragma("unroll")                                                      \
        for (int ks = 0; ks < 2; ++ks) {                                       \
          int kk = ks * 32 + k0;                                               \
          bf16x8 bv0 = *(const bf16x8*)&vT[lh][(0 + p) * 72 + kk];             \
          bf16x8 bv1 = *(const bf16x8*)&vT[lh][(16 + p) * 72 + kk];            \
          bf16x8 ap = *(const bf16x8*)&Ph[(rb_ + p) * 72 + kk];                \
          o0 = MFMA16(ap, bv0, o0);                                            \
          o1 = MFMA16(ap, bv1, o1);                                            \
        }                                                                      \
        size_t ob = (size_t)w * 12288 + (size_t)(rb_ + q8 * 4) * 192 +         \
                    ((PH) * 2 + lh) * 32 + p;                                  \
        _Pragma("unroll")                                                      \
        for (int r = 0; r < 4; ++r) {                                          \
          obuf[ob + (size_t)r * 192]      = f2b(o0[r]);                        \
          obuf[ob + (size_t)r * 192 + 16] = f2b(o1[r]);                        \
        }                                                                      \
      }                                                                        \
    }                                                                          \
  }

// ---------------- K_a: qkv + attention (reads windowed xn; O in place) -----
__global__ __launch_bounds__(768, 3) void attn_kernel(
    const ushort_t* __restrict__ buf_xn,   // windowed xn (read), also O dest
    const ushort_t* __restrict__ qkvT, const float* __restrict__ qkv_b,
    ushort_t* __restrict__ obuf) {
  int w = blockIdx.x;
  int tid = threadIdx.x;
  int wave = tid >> 6, lane = tid & 63;
  int p = lane & 15, q8 = lane >> 4;

  __shared__ __align__(16) ushort_t tile[64][200];  // xn (token-major) 25600 B
  __shared__ __align__(16) ushort_t qkP[2][5120];   // q|k -> P, per head 10240 B
  __shared__ __align__(16) ushort_t vT[2][2304];    // v^T [32][72] 4608 B/head

  // ---- phase 0: coalesced copy buf -> tile ----
  const ushort_t* bw = buf_xn + (size_t)w * 12288;
#pragma unroll
  for (int it = 0; it < 2; ++it) {
    int u = it * 768 + tid;
    int token = u / 24, cv = u - token * 24;
    *(u16x8*)&tile[token][cv * 8] = *(const u16x8*)&bw[u * 8];
  }
  __syncthreads();   // B1

  const f32x4 zz = {0.f, 0.f, 0.f, 0.f};

  QKV_ATTN_PASS(0)
  __syncthreads();   // B4
  QKV_ATTN_PASS(1)
  __syncthreads();   // B4
  QKV_ATTN_PASS(2)
}

// ---------------- K_b: proj GEMM + residual-1 -> x_mid (in place) ----------
__global__ __launch_bounds__(256) void proj_kernel(
    ushort_t* __restrict__ buf,           // in: O, out: x_mid (windowed)
    const ushort_t* __restrict__ projT, const float* __restrict__ proj_b,
    const float* __restrict__ x, float2* __restrict__ gpart) {
  int w = blockIdx.x;
  int b = w >> 10, wh = (w >> 5) & 31, ww = w & 31;
  int tid = threadIdx.x;
  int wave = tid >> 6, lane = tid & 63;
  int p = lane & 15, q8 = lane >> 4;
  int C3 = lane >> 3, I = lane & 7;

  __shared__ __align__(16) ushort_t otile[64][200];  // O -> proj-out -> resid
  __shared__ __align__(16) float2 red[1536];

  ushort_t* bw = buf + (size_t)w * 12288;

  // ---- load O tile (coalesced) ----
#pragma unroll
  for (int it = 0; it < 6; ++it) {
    int idx = (it * 256 + tid) * 8;       // entry index, 8-aligned
    int t = idx / 192, c = idx - t * 192;
    *(u16x8*)&otile[t][c] = *(const u16x8*)&bw[idx];
  }
  __syncthreads();

  // ---- proj GEMM: 12 col-tiles over 4 waves (3 rounds, static acc) ----
  const f32x4 zz = {0.f, 0.f, 0.f, 0.f};
  f32x4 prr[3][4];
#pragma unroll
  for (int rd = 0; rd < 3; ++rd) {
    int col = rd * 64 + wave * 16 + p;
#pragma unroll
    for (int mt = 0; mt < 4; ++mt) prr[rd][mt] = zz;
#pragma unroll
    for (int ks = 0; ks < 6; ++ks) {
      int k0 = ks * 32 + q8 * 8;
      bf16x8 bfr = *(const bf16x8*)(projT + (size_t)col * DIM + k0);
      prr[rd][0] = MFMA16(*(const bf16x8*)&otile[0 * 16 + p][k0], bfr, prr[rd][0]);
      prr[rd][1] = MFMA16(*(const bf16x8*)&otile[1 * 16 + p][k0], bfr, prr[rd][1]);
      prr[rd][2] = MFMA16(*(const bf16x8*)&otile[2 * 16 + p][k0], bfr, prr[rd][2]);
      prr[rd][3] = MFMA16(*(const bf16x8*)&otile[3 * 16 + p][k0], bfr, prr[rd][3]);
    }
  }
  __syncthreads();   // all otile reads done

  // ---- write proj-out (+bias) back into otile ----
#pragma unroll
  for (int rd = 0; rd < 3; ++rd) {
    int col = rd * 64 + wave * 16 + p;
    float bias = proj_b[col];
#pragma unroll
    for (int mt = 0; mt < 4; ++mt)
#pragma unroll
      for (int r = 0; r < 4; ++r)
        otile[mt * 16 + q8 * 4 + r][col] = f2b(prr[rd][mt][r] + bias);
  }
  __syncthreads();

  int px0 = (ww << 3) + 4;
  int px1 = (px0 + 4) & 255;

  // ---- in-place residual (token-major via xpose8) ----
#pragma unroll
  for (int it = 0; it < 6; ++it) {
    int u = it * 256 + tid;
    int c = u >> 3, i = u & 7;
    int cbase = it * 32 + wave * 8;
    u16x8 rr = *(const u16x8*)&otile[I * 8 + C3][cbase];
    ushort_t V[8];
#pragma unroll
    for (int j = 0; j < 8; ++j) V[j] = rr[j];
    xpose8(V, C3);   // V[j] = proj-out(channel c, token i*8+j)
    int py = ((wh << 3) + i + 4) & 255;
    const float* src = x + (((size_t)(b * DIM + c)) << 16) + (py << 8);
    float4 ra = *(const float4*)(src + px0);
    V[0] = f2b(ra.x + b2f(V[0]));
    V[1] = f2b(ra.y + b2f(V[1]));
    V[2] = f2b(ra.z + b2f(V[2]));
    V[3] = f2b(ra.w + b2f(V[3]));
    float4 rb2 = *(const float4*)(src + px1);
    V[4] = f2b(rb2.x + b2f(V[4]));
    V[5] = f2b(rb2.y + b2f(V[5]));
    V[6] = f2b(rb2.z + b2f(V[6]));
    V[7] = f2b(rb2.w + b2f(V[7]));
    xpose8(V, C3);   // back to (channel cbase+j, token I*8+C3)
    u16x8 wv;
#pragma unroll
    for (int j = 0; j < 8; ++j) wv[j] = V[j];
    *(u16x8*)&otile[I * 8 + C3][cbase] = wv;   // same addr as read: wave-local RMW
  }
  __syncthreads();

  // ---- coalesced write back to buf (now x_mid) + GN2 partials ----
#pragma unroll
  for (int it = 0; it < 6; ++it) {
    int u = it * 256 + tid;
    int token = u / 24, cv = u - token * 24;
    u16x8 v = *(const u16x8*)&otile[token][cv * 8];
    *(u16x8*)&bw[u * 8] = v;
    float s_ = 0.f, s2_ = 0.f;
#pragma unroll
    for (int t = 0; t < 8; ++t) { float f = b2f(v[t]); s_ += f; s2_ += f * f; }
    red[u] = make_float2(s_, s2_);
  }
  __syncthreads();

  for (int g = wave; g < 8; g += 4) {
    float s_ = 0.f, s2_ = 0.f;
#pragma unroll
    for (int j = 0; j < 3; ++j) {
      float2 t_ = red[lane * 24 + g * 3 + j];
      s_ += t_.x; s2_ += t_.y;
    }
    for (int m = 1; m < 64; m <<= 1) { s_ += __shfl_xor(s_, m); s2_ += __shfl_xor(s2_, m); }
    if (lane == 0) gpart[(size_t)w * 8 + g] = make_float2(s_, s2_);
  }
}

// ---------------- fused GN2 + MLP + residual2 (r10-best config) ------------
// 4 waves, chunk=64 hidden, fully-unrolled chunk loop (cross-chunk pipelining).
__global__ __launch_bounds__(256, 4) void mlp_kernel(
    const ushort_t* __restrict__ x_mid,
    const ushort_t* __restrict__ w1T, const float* __restrict__ b1,
    const ushort_t* __restrict__ w2T, const float* __restrict__ b2,
    const float* __restrict__ stats2,
    const float* __restrict__ n2w, const float* __restrict__ n2b,
    float* __restrict__ out) {
  int bid = blockIdx.x;
  int b = bid >> 10, y = (bid >> 2) & 255, xq = bid & 3;
  int x0 = xq * 64;
  int tid = threadIdx.x;
  int wave = tid >> 6, lane = tid & 63;
  int p = lane & 15, q = lane >> 4;

  __shared__ ushort_t xn[64][200];   // xn tile, later mlp-out staging
  __shared__ ushort_t hb[64][72];    // hidden chunk [token][hid]
  __shared__ float gw2[192], gb2[192];

  int yp = (y + 252) & 255;          // (y - 4) mod 256
  int whp = yp >> 3, ip = yp & 7;
  size_t winrow = ((size_t)b * 1024 + (size_t)whp * 32) * 12288;

  if (tid < 192) {
    int g = tid / 24;
    float mean = stats2[(b * 8 + g) * 2], rstd = stats2[(b * 8 + g) * 2 + 1];
    float w_ = n2w[tid] * rstd;
    gw2[tid] = w_;
    gb2[tid] = n2b[tid] - mean * w_;
  }
  __syncthreads();

  for (int u = tid; u < 1536; u += 256) {
    int tx = u / 24, ch = u - tx * 24;
    int c8 = ch * 8;
    int xp = (x0 + tx + 252) & 255;  // (x - 4) mod 256
    u16x8 v = *(const u16x8*)(x_mid + winrow + (size_t)(xp >> 3) * 12288 +
                              (size_t)(ip * 8 + (xp & 7)) * 192 + c8);
    u16x8 o;
#pragma unroll
    for (int t = 0; t < 8; ++t) {
      int c = c8 + t;
      o[t] = f2b(fmaf(b2f(v[t]), gw2[c], gb2[c]));
    }
    *(u16x8*)&xn[tx][c8] = o;
  }
  __syncthreads();

  const f32x4 zz = {0.f, 0.f, 0.f, 0.f};
  f32x4 accO[4][3];
#pragma unroll
  for (int mt = 0; mt < 4; ++mt)
#pragma unroll
    for (int nt = 0; nt < 3; ++nt) accO[mt][nt] = zz;

  for (int ch = 0; ch < 12; ++ch) {
    // GEMM1 (swapped): a1[mt] holds D[hidden=q*4+r (+wave*16)][token=mt*16+p]
    int hcol16 = ch * 64 + wave * 16;
    f32x4 a1[4];
#pragma unroll
    for (int mt = 0; mt < 4; ++mt) a1[mt] = zz;
#pragma unroll
    for (int ks = 0; ks < 6; ++ks) {
      int k0 = ks * 32 + q * 8;
      bf16x8 wfr = *(const bf16x8*)(w1T + (size_t)(hcol16 + p) * DIM + k0);
#pragma unroll
      for (int mt = 0; mt < 4; ++mt) {
        bf16x8 afr = *(const bf16x8*)&xn[mt * 16 + p][k0];
        a1[mt] = MFMA16(wfr, afr, a1[mt]);   // swapped: weights=rows, tokens=cols
      }
    }
    float4 bb = *(const float4*)&b1[hcol16 + q * 4];
    if (ch) __syncthreads();     // previous chunk's GEMM2 readers done
#pragma unroll
    for (int mt = 0; mt < 4; ++mt) {
      u16x4 hv;
#pragma unroll
      for (int r = 0; r < 4; ++r) {
        float vv = a1[mt][r] + ((const float*)&bb)[r];
        float g = vv / (1.0f + __expf(-1.702f * vv));   // sigmoid-GELU
        hv[r] = f2b(g);
      }
      *(u16x4*)&hb[mt * 16 + p][wave * 16 + q * 4] = hv;
    }
    __syncthreads();
    // GEMM2: accO += gelu(H) @ W2[chunk,:]
#pragma unroll
    for (int ks = 0; ks < 2; ++ks) {
      int k0 = ks * 32 + q * 8;
#pragma unroll
      for (int mt = 0; mt < 4; ++mt) {
        bf16x8 afr = *(const bf16x8*)&hb[mt * 16 + p][k0];
#pragma unroll
        for (int nt = 0; nt < 3; ++nt) {
          bf16x8 bfr = *(const bf16x8*)(w2T + (size_t)(wave * 48 + nt * 16 + p) * HID + ch * 64 + k0);
          accO[mt][nt] = MFMA16(afr, bfr, accO[mt][nt]);
        }
      }
    }
  }
  __syncthreads();

#pragma unroll
  for (int mt = 0; mt < 4; ++mt)
#pragma unroll
    for (int nt = 0; nt < 3; ++nt) {
      int col = wave * 48 + nt * 16 + p;
      float bias = b2[col];
#pragma unroll
      for (int r = 0; r < 4; ++r)
        xn[mt * 16 + q * 4 + r][col] = f2b(accO[mt][nt][r] + bias);
    }
  __syncthreads();

  // coalesced fp32 out stores: wave = 64 consecutive x for one 8-ch chunk
#pragma unroll
  for (int cg = 0; cg < 6; ++cg) {
    int chunk = (tid >> 6) + cg * 4;          // 0..23
    int txx = tid & 63;
    int c8 = chunk * 8;
    int xp = (x0 + txx + 252) & 255;
    u16x8 raw = *(const u16x8*)(x_mid + winrow + (size_t)(xp >> 3) * 12288 +
                                (size_t)(ip * 8 + (xp & 7)) * 192 + c8);
    u16x8 mo = *(const u16x8*)&xn[txx][c8];
#pragma unroll
    for (int t = 0; t < 8; ++t) {
      out[(((size_t)(b * DIM + c8 + t)) << 16) + (y << 8) + x0 + txx] =
          b2f(raw[t]) + b2f(mo[t]);
    }
  }
}

// ---------------- host launcher --------------------------------------------
extern "C" void kernel_launch(void* const* d_in, const int* in_sizes, int n_in,
                              void* d_out, int out_size, void* d_ws, size_t ws_size,
                              hipStream_t stream) {
  const float* x      = (const float*)d_in[0];
  const float* qkv_w  = (const float*)d_in[1];
  const float* qkv_b  = (const float*)d_in[2];
  const float* proj_w = (const float*)d_in[3];
  const float* proj_b = (const float*)d_in[4];
  const float* n1w    = (const float*)d_in[5];
  const float* n1b    = (const float*)d_in[6];
  const float* n2w    = (const float*)d_in[7];
  const float* n2b    = (const float*)d_in[8];
  const float* mlp_w1 = (const float*)d_in[9];
  const float* mlp_b1 = (const float*)d_in[10];
  const float* mlp_w2 = (const float*)d_in[11];
  const float* mlp_b2 = (const float*)d_in[12];
  float* out = (float*)d_out;

  char* ws = (char*)d_ws;
  const size_t XMID_B = (size_t)NWIN * 64 * DIM * 2;          // 100663296
  ushort_t* buf   = (ushort_t*)ws;     // xn_win -> O -> x_mid (same region)
  ushort_t* qkvT  = (ushort_t*)(ws + XMID_B);
  ushort_t* projT = (ushort_t*)(ws + XMID_B + 221184);
  ushort_t* w1T   = (ushort_t*)(ws + XMID_B + 221184 + 73728);
  ushort_t* w2T   = (ushort_t*)(ws + XMID_B + 221184 + 73728 + 294912);
  float* partial  = (float*)(ws + XMID_B + 884736);
  float* stats1   = (float*)(ws + XMID_B + 884736 + 16384);
  float* stats2   = (float*)(ws + XMID_B + 884736 + 16384 + 256);
  float2* gpart   = (float2*)(ws + XMID_B + 884736 + 16384 + 512);

  transpose_w<<<(576 * 192 + 255) / 256, 256, 0, stream>>>(qkv_w, qkvT, 192, 576);
  transpose_w<<<(192 * 192 + 255) / 256, 256, 0, stream>>>(proj_w, projT, 192, 192);
  transpose_w<<<(768 * 192 + 255) / 256, 256, 0, stream>>>(mlp_w1, w1T, 192, 768);
  transpose_w<<<(192 * 768 + 255) / 256, 256, 0, stream>>>(mlp_w2, w2T, 768, 192);

  gn_stats1_f32<<<32 * 64, 256, 0, stream>>>(x, partial);
  gn_stats2<<<32, 64, 0, stream>>>(partial, stats1);

  norm1_win<<<NWIN, 256, 0, stream>>>(x, stats1, n1w, n1b, buf);

  attn_kernel<<<NWIN, 768, 0, stream>>>(buf, qkvT, qkv_b, buf);

  proj_kernel<<<NWIN, 256, 0, stream>>>(buf, projT, proj_b, x, gpart);

  gn2_reduce<<<32, 64, 0, stream>>>(gpart, stats2);

  mlp_kernel<<<NWIN, 256, 0, stream>>>(buf, w1T, mlp_b1, w2T, mlp_b2,
                                       stats2, n2w, n2b, out);
}